// Round 3
// baseline (848.710 us; speedup 1.0000x reference)
//
#include <hip/hip_runtime.h>

#define N_NODES 100000
#define N_EDGES 1600000
#define IN_F 256
#define OUT_F 64
#define NPAD 100096
#define NB 391            // node buckets of 256 nodes (99999>>8 = 390)
#define NBLK 200          // partition blocks
#define CHUNK 8000        // edges per partition block (200*8000 = 1.6M exact)
#define MSIZE (2*NB*NBLK) // 156400 (dst matrix then src matrix)
#define SC_BLOCKS 612     // ceil(MSIZE/256)

// --- A: per-block bucket histograms (dst and src), no global atomics ---
__global__ __launch_bounds__(256) void histA_kernel(const int* __restrict__ src,
                                                    const int* __restrict__ dst,
                                                    int* __restrict__ hist_g) {
    __shared__ int hD[NB], hS[NB];
    int b = blockIdx.x, t = threadIdx.x;
    for (int j = t; j < NB; j += 256) { hD[j] = 0; hS[j] = 0; }
    __syncthreads();
    int e0 = b * CHUNK;
    for (int e = e0 + t; e < e0 + CHUNK; e += 256) {
        atomicAdd(&hD[dst[e] >> 8], 1);
        atomicAdd(&hS[src[e] >> 8], 1);
    }
    __syncthreads();
    for (int j = t; j < NB; j += 256) {
        hist_g[j * NBLK + b] = hD[j];
        hist_g[NB * NBLK + j * NBLK + b] = hS[j];
    }
}

// --- exclusive scan of hist_g[MSIZE] (in-place), 3 kernels ---
__global__ __launch_bounds__(256) void scan1_kernel(int* __restrict__ data,
                                                    int* __restrict__ partials) {
    __shared__ int sm[256];
    int i = blockIdx.x * 256 + threadIdx.x;
    int v = (i < MSIZE) ? data[i] : 0;
    sm[threadIdx.x] = v;
    __syncthreads();
    int x = v;
    #pragma unroll
    for (int off = 1; off < 256; off <<= 1) {
        int tv = 0;
        if ((int)threadIdx.x >= off) tv = sm[threadIdx.x - off];
        __syncthreads();
        x += tv;
        sm[threadIdx.x] = x;
        __syncthreads();
    }
    if (i < MSIZE) data[i] = x - v;  // exclusive within block
    if (threadIdx.x == 255) partials[blockIdx.x] = x;
}

__global__ __launch_bounds__(1024) void scan2_kernel(int* __restrict__ partials) {
    __shared__ int sm[1024];
    int i = threadIdx.x;
    int v = (i < SC_BLOCKS) ? partials[i] : 0;
    sm[i] = v;
    __syncthreads();
    int x = v;
    #pragma unroll
    for (int off = 1; off < 1024; off <<= 1) {
        int tv = 0;
        if (i >= off) tv = sm[i - off];
        __syncthreads();
        x += tv;
        sm[i] = x;
        __syncthreads();
    }
    if (i < SC_BLOCKS) partials[i] = x - v;  // exclusive
}

__global__ __launch_bounds__(256) void scan3_kernel(int* __restrict__ data,
                                                    const int* __restrict__ partials,
                                                    int* __restrict__ base_d,
                                                    int* __restrict__ base_s) {
    int i = blockIdx.x * 256 + threadIdx.x;
    if (i < MSIZE) {
        int v = data[i] + partials[blockIdx.x];
        data[i] = v;
        if (i % NBLK == 0) {
            int q = i / NBLK;
            if (q < NB) base_d[q] = v;
            else        base_s[q - NB] = v - N_EDGES;
        }
    }
    if (i == 0) { base_d[NB] = N_EDGES; base_s[NB] = N_EDGES; }
}

// --- C: partition edges into dst-buckets (packed) and src keys into src-buckets ---
__global__ __launch_bounds__(256) void part_kernel(const int* __restrict__ src,
                                                   const int* __restrict__ dst,
                                                   const int* __restrict__ hist_g,
                                                   unsigned* __restrict__ edge_buf,
                                                   int* __restrict__ src_part) {
    __shared__ int curD[NB], curS[NB];
    int b = blockIdx.x, t = threadIdx.x;
    for (int j = t; j < NB; j += 256) {
        curD[j] = hist_g[j * NBLK + b];
        curS[j] = hist_g[NB * NBLK + j * NBLK + b] - N_EDGES;
    }
    __syncthreads();
    int e0 = b * CHUNK;
    for (int e = e0 + t; e < e0 + CHUNK; e += 256) {
        int s = src[e], d = dst[e];
        int pD = atomicAdd(&curD[d >> 8], 1);
        edge_buf[pD] = ((unsigned)(d & 255) << 17) | (unsigned)s;
        int pS = atomicAdd(&curS[s >> 8], 1);
        src_part[pS] = s;
    }
}

// --- per-bucket degree -> norm (src side) ---
__global__ __launch_bounds__(256) void normout_kernel(const int* __restrict__ src_part,
                                                      const int* __restrict__ base_s,
                                                      float* __restrict__ norm_out) {
    __shared__ int hist[256];
    int j = blockIdx.x, t = threadIdx.x;
    hist[t] = 0;
    __syncthreads();
    int b0 = base_s[j], b1 = base_s[j + 1];
    for (int e = b0 + t; e < b1; e += 256)
        atomicAdd(&hist[src_part[e] & 255], 1);
    __syncthreads();
    int node = j * 256 + t;
    if (node < N_NODES) {
        int d = hist[t]; if (d < 1) d = 1;
        norm_out[node] = rsqrtf((float)d);
    }
}

// --- per-bucket degree -> norm (dst side, from packed edge_buf) ---
__global__ __launch_bounds__(256) void normin_kernel(const unsigned* __restrict__ edge_buf,
                                                     const int* __restrict__ base_d,
                                                     float* __restrict__ norm_in) {
    __shared__ int hist[256];
    int j = blockIdx.x, t = threadIdx.x;
    hist[t] = 0;
    __syncthreads();
    int b0 = base_d[j], b1 = base_d[j + 1];
    for (int e = b0 + t; e < b1; e += 256)
        atomicAdd(&hist[edge_buf[e] >> 17], 1);
    __syncthreads();
    int node = j * 256 + t;
    if (node < N_NODES) {
        int d = hist[t]; if (d < 1) d = 1;
        norm_in[node] = rsqrtf((float)d);
    }
}

// --- GEMM: h[r][c] = (sum_k feat[r][k]*W[k][c]) * norm_out[r] ---
__global__ __launch_bounds__(256) void gemm_kernel(const float* __restrict__ feat,
                                                   const float* __restrict__ W,
                                                   const float* __restrict__ norm_out,
                                                   float* __restrict__ h) {
    __shared__ float As[64][68];
    __shared__ float Bs[64][68];
    const int tid  = threadIdx.x;
    const int tx   = tid & 15;
    const int ty   = tid >> 4;
    const int row0 = blockIdx.x * 64;
    const int lrow = tid >> 2;
    const int lc   = (tid & 3) * 16;

    float4 acc[4];
    #pragma unroll
    for (int i = 0; i < 4; ++i) acc[i] = make_float4(0.f, 0.f, 0.f, 0.f);

    for (int ks = 0; ks < IN_F; ks += 64) {
        const int gr = row0 + lrow;
        #pragma unroll
        for (int q = 0; q < 4; ++q) {
            float4 v = make_float4(0.f, 0.f, 0.f, 0.f);
            if (gr < N_NODES)
                v = *(const float4*)&feat[(long)gr * IN_F + ks + lc + 4 * q];
            *(float4*)&As[lrow][lc + 4 * q] = v;
            *(float4*)&Bs[lrow][lc + 4 * q] =
                *(const float4*)&W[(ks + lrow) * OUT_F + lc + 4 * q];
        }
        __syncthreads();
        #pragma unroll
        for (int kq = 0; kq < 16; ++kq) {
            float4 a0 = *(const float4*)&As[ty +  0][4 * kq];
            float4 a1 = *(const float4*)&As[ty + 16][4 * kq];
            float4 a2 = *(const float4*)&As[ty + 32][4 * kq];
            float4 a3 = *(const float4*)&As[ty + 48][4 * kq];
            float4 b0 = *(const float4*)&Bs[4 * kq + 0][4 * tx];
            float4 b1 = *(const float4*)&Bs[4 * kq + 1][4 * tx];
            float4 b2 = *(const float4*)&Bs[4 * kq + 2][4 * tx];
            float4 b3 = *(const float4*)&Bs[4 * kq + 3][4 * tx];
#define FMA4(ACC, S, B) \
            ACC.x = fmaf(S, B.x, ACC.x); ACC.y = fmaf(S, B.y, ACC.y); \
            ACC.z = fmaf(S, B.z, ACC.z); ACC.w = fmaf(S, B.w, ACC.w);
            FMA4(acc[0], a0.x, b0) FMA4(acc[0], a0.y, b1) FMA4(acc[0], a0.z, b2) FMA4(acc[0], a0.w, b3)
            FMA4(acc[1], a1.x, b0) FMA4(acc[1], a1.y, b1) FMA4(acc[1], a1.z, b2) FMA4(acc[1], a1.w, b3)
            FMA4(acc[2], a2.x, b0) FMA4(acc[2], a2.y, b1) FMA4(acc[2], a2.z, b2) FMA4(acc[2], a2.w, b3)
            FMA4(acc[3], a3.x, b0) FMA4(acc[3], a3.y, b1) FMA4(acc[3], a3.z, b2) FMA4(acc[3], a3.w, b3)
#undef FMA4
        }
        __syncthreads();
    }
    #pragma unroll
    for (int i = 0; i < 4; ++i) {
        int r = row0 + ty + 16 * i;
        if (r < N_NODES) {
            float s = norm_out[r];
            float4 o = acc[i];
            o.x *= s; o.y *= s; o.z *= s; o.w *= s;
            *(float4*)&h[(long)r * OUT_F + 4 * tx] = o;
        }
    }
}

// --- aggregate: one block per dst-bucket, LDS accumulator [256][64] ---
__global__ __launch_bounds__(256) void agg_kernel(const unsigned* __restrict__ edge_buf,
                                                  const int* __restrict__ base_d,
                                                  const float* __restrict__ h,
                                                  const float* __restrict__ norm_in,
                                                  const float* __restrict__ bias,
                                                  float* __restrict__ out) {
    extern __shared__ float accum[];  // 256*64 floats = 64 KB
    int t = threadIdx.x, j = blockIdx.x;
    int lane = t & 63, wave = t >> 6;
    for (int i = t; i < 256 * OUT_F; i += 256) accum[i] = 0.f;
    __syncthreads();
    float bias_r = bias[lane];
    int b0 = base_d[j], b1 = base_d[j + 1];
    for (int e = b0 + wave * 8; e < b1; e += 32) {
        #pragma unroll
        for (int k = 0; k < 8; ++k) {
            int ee = e + k;
            if (ee < b1) {
                unsigned p = edge_buf[ee];
                int s  = (int)(p & 0x1FFFFu);
                int dl = (int)(p >> 17);
                float v = h[(size_t)s * OUT_F + lane];
                atomicAdd(&accum[dl * OUT_F + lane], v);
            }
        }
    }
    __syncthreads();
    #pragma unroll 4
    for (int nb = 0; nb < 256; nb += 4) {
        int nl = nb + wave;
        int node = j * 256 + nl;
        if (node < N_NODES) {
            float norm = norm_in[node];
            float v = accum[nl * OUT_F + lane] * norm + bias_r;
            out[(size_t)node * OUT_F + lane] = fmaxf(v, 0.f);
        }
    }
}

extern "C" void kernel_launch(void* const* d_in, const int* in_sizes, int n_in,
                              void* d_out, int out_size, void* d_ws, size_t ws_size,
                              hipStream_t stream) {
    const float* feat = (const float*)d_in[0];
    const float* W    = (const float*)d_in[1];
    const float* bias = (const float*)d_in[2];
    const int*   src  = (const int*)d_in[3];
    const int*   dst  = (const int*)d_in[4];
    float* out = (float*)d_out;

    char* w = (char*)d_ws;
    size_t off = 0;
    auto take = [&](size_t bytes) { char* p = w + off; off += (bytes + 255) & ~(size_t)255; return p; };

    int*      hist_g   = (int*)take((size_t)MSIZE * 4);
    int*      partials = (int*)take((size_t)SC_BLOCKS * 4);
    int*      base_d   = (int*)take((size_t)(NB + 1) * 4);
    int*      base_s   = (int*)take((size_t)(NB + 1) * 4);
    float*    norm_out = (float*)take((size_t)NPAD * 4);
    float*    norm_in  = (float*)take((size_t)NPAD * 4);
    unsigned* edge_buf = (unsigned*)take((size_t)N_EDGES * 4);
    float*    h        = (float*)take((size_t)N_NODES * OUT_F * 4);
    int*      src_part = (int*)h;  // alias: consumed by normout before gemm writes h

    histA_kernel<<<NBLK, 256, 0, stream>>>(src, dst, hist_g);
    scan1_kernel<<<SC_BLOCKS, 256, 0, stream>>>(hist_g, partials);
    scan2_kernel<<<1, 1024, 0, stream>>>(partials);
    scan3_kernel<<<SC_BLOCKS, 256, 0, stream>>>(hist_g, partials, base_d, base_s);
    part_kernel<<<NBLK, 256, 0, stream>>>(src, dst, hist_g, edge_buf, src_part);
    normout_kernel<<<NB, 256, 0, stream>>>(src_part, base_s, norm_out);
    normin_kernel<<<NB, 256, 0, stream>>>(edge_buf, base_d, norm_in);
    gemm_kernel<<<(N_NODES + 63) / 64, 256, 0, stream>>>(feat, W, norm_out, h);
    agg_kernel<<<NB, 256, 256 * OUT_F * 4, stream>>>(edge_buf, base_d, h, norm_in, bias, out);
}

// Round 4
// 201.102 us; speedup vs baseline: 4.2203x; 4.2203x over previous
//
#include <hip/hip_runtime.h>

#define N_NODES 100000
#define N_EDGES 1600000
#define IN_F 256
#define OUT_F 64
#define NPAD 100096
#define NB 391            // node buckets of 256 nodes
#define NBLK 200          // partition blocks
#define CHUNK 8000        // edges per partition block (200*8000 = 1.6M exact)
#define MSIZE (2*NB*NBLK) // dst matrix then src matrix
#define SC_BLOCKS 612     // ceil(MSIZE/256)
#define CAP 12288         // LDS staging capacity per bucket (mean 4096, sigma 64)

// --- per-block bucket histograms (dst and src), no global atomics ---
__global__ __launch_bounds__(256) void histA_kernel(const int* __restrict__ src,
                                                    const int* __restrict__ dst,
                                                    int* __restrict__ hist_g) {
    __shared__ int hD[NB], hS[NB];
    int b = blockIdx.x, t = threadIdx.x;
    for (int j = t; j < NB; j += 256) { hD[j] = 0; hS[j] = 0; }
    __syncthreads();
    int e0 = b * CHUNK;
    for (int e = e0 + t; e < e0 + CHUNK; e += 256) {
        atomicAdd(&hD[dst[e] >> 8], 1);
        atomicAdd(&hS[src[e] >> 8], 1);
    }
    __syncthreads();
    for (int j = t; j < NB; j += 256) {
        hist_g[j * NBLK + b] = hD[j];
        hist_g[NB * NBLK + j * NBLK + b] = hS[j];
    }
}

// --- exclusive scan of hist_g[MSIZE] (in-place), 3 kernels ---
__global__ __launch_bounds__(256) void scan1_kernel(int* __restrict__ data,
                                                    int* __restrict__ partials) {
    __shared__ int sm[256];
    int i = blockIdx.x * 256 + threadIdx.x;
    int v = (i < MSIZE) ? data[i] : 0;
    sm[threadIdx.x] = v;
    __syncthreads();
    int x = v;
    #pragma unroll
    for (int off = 1; off < 256; off <<= 1) {
        int tv = 0;
        if ((int)threadIdx.x >= off) tv = sm[threadIdx.x - off];
        __syncthreads();
        x += tv;
        sm[threadIdx.x] = x;
        __syncthreads();
    }
    if (i < MSIZE) data[i] = x - v;
    if (threadIdx.x == 255) partials[blockIdx.x] = x;
}

__global__ __launch_bounds__(1024) void scan2_kernel(int* __restrict__ partials) {
    __shared__ int sm[1024];
    int i = threadIdx.x;
    int v = (i < SC_BLOCKS) ? partials[i] : 0;
    sm[i] = v;
    __syncthreads();
    int x = v;
    #pragma unroll
    for (int off = 1; off < 1024; off <<= 1) {
        int tv = 0;
        if (i >= off) tv = sm[i - off];
        __syncthreads();
        x += tv;
        sm[i] = x;
        __syncthreads();
    }
    if (i < SC_BLOCKS) partials[i] = x - v;
}

__global__ __launch_bounds__(256) void scan3_kernel(int* __restrict__ data,
                                                    const int* __restrict__ partials,
                                                    int* __restrict__ base_d,
                                                    int* __restrict__ base_s) {
    int i = blockIdx.x * 256 + threadIdx.x;
    if (i < MSIZE) {
        int v = data[i] + partials[blockIdx.x];
        data[i] = v;
        if (i % NBLK == 0) {
            int q = i / NBLK;
            if (q < NB) base_d[q] = v;
            else        base_s[q - NB] = v - N_EDGES;
        }
    }
    if (i == 0) { base_d[NB] = N_EDGES; base_s[NB] = N_EDGES; }
}

// --- partition edges into dst-buckets (packed dlocal|src) and src keys into src-buckets ---
__global__ __launch_bounds__(256) void part_kernel(const int* __restrict__ src,
                                                   const int* __restrict__ dst,
                                                   const int* __restrict__ hist_g,
                                                   unsigned* __restrict__ edge_buf,
                                                   int* __restrict__ src_part) {
    __shared__ int curD[NB], curS[NB];
    int b = blockIdx.x, t = threadIdx.x;
    for (int j = t; j < NB; j += 256) {
        curD[j] = hist_g[j * NBLK + b];
        curS[j] = hist_g[NB * NBLK + j * NBLK + b] - N_EDGES;
    }
    __syncthreads();
    int e0 = b * CHUNK;
    for (int e = e0 + t; e < e0 + CHUNK; e += 256) {
        int s = src[e], d = dst[e];
        int pD = atomicAdd(&curD[d >> 8], 1);
        edge_buf[pD] = ((unsigned)(d & 255) << 17) | (unsigned)s;
        int pS = atomicAdd(&curS[s >> 8], 1);
        src_part[pS] = s;
    }
}

// --- per-bucket out-degree -> norm_out ---
__global__ __launch_bounds__(256) void normout_kernel(const int* __restrict__ src_part,
                                                      const int* __restrict__ base_s,
                                                      float* __restrict__ norm_out) {
    __shared__ int hist[256];
    int j = blockIdx.x, t = threadIdx.x;
    hist[t] = 0;
    __syncthreads();
    int b0 = base_s[j], b1 = base_s[j + 1];
    for (int e = b0 + t; e < b1; e += 256)
        atomicAdd(&hist[src_part[e] & 255], 1);
    __syncthreads();
    int node = j * 256 + t;
    if (node < N_NODES) {
        int d = hist[t]; if (d < 1) d = 1;
        norm_out[node] = rsqrtf((float)d);
    }
}

// --- per-bucket in-LDS counting sort: edge_buf bucket region -> dst-sorted CSR (in place)
//     also emits row_ptr[node] = global CSR start.
__global__ __launch_bounds__(256) void bucket_kernel(unsigned* __restrict__ edge_buf,
                                                     const int* __restrict__ base_d,
                                                     int* __restrict__ row_ptr) {
    __shared__ unsigned stage[CAP];   // 48 KB
    __shared__ int hist[256];
    __shared__ int cur[256];
    int j = blockIdx.x, t = threadIdx.x;
    int b0 = base_d[j], b1 = base_d[j + 1];
    int cnt = b1 - b0;
    hist[t] = 0;
    __syncthreads();
    for (int i = t; i < cnt; i += 256) {
        unsigned p = edge_buf[b0 + i];
        stage[i] = p;
        atomicAdd(&hist[p >> 17], 1);
    }
    __syncthreads();
    int v = hist[t];
    cur[t] = v;
    __syncthreads();
    int x = v;
    #pragma unroll
    for (int off = 1; off < 256; off <<= 1) {
        int tv = (t >= off) ? cur[t - off] : 0;
        __syncthreads();
        x += tv;
        cur[t] = x;
        __syncthreads();
    }
    int excl = x - v;                 // exclusive local prefix
    row_ptr[j * 256 + t] = b0 + excl;
    cur[t] = excl;
    __syncthreads();
    for (int i = t; i < cnt; i += 256) {
        unsigned p = stage[i];
        int pos = atomicAdd(&cur[p >> 17], 1);
        edge_buf[b0 + pos] = p & 0x1FFFFu;   // store src id
    }
}

// --- GEMM: h[r][c] = (sum_k feat[r][k]*W[k][c]) * norm_out[r] ---
__global__ __launch_bounds__(256) void gemm_kernel(const float* __restrict__ feat,
                                                   const float* __restrict__ W,
                                                   const float* __restrict__ norm_out,
                                                   float* __restrict__ h) {
    __shared__ float As[64][68];
    __shared__ float Bs[64][68];
    const int tid  = threadIdx.x;
    const int tx   = tid & 15;
    const int ty   = tid >> 4;
    const int row0 = blockIdx.x * 64;
    const int lrow = tid >> 2;
    const int lc   = (tid & 3) * 16;

    float4 acc[4];
    #pragma unroll
    for (int i = 0; i < 4; ++i) acc[i] = make_float4(0.f, 0.f, 0.f, 0.f);

    for (int ks = 0; ks < IN_F; ks += 64) {
        const int gr = row0 + lrow;
        #pragma unroll
        for (int q = 0; q < 4; ++q) {
            float4 v = make_float4(0.f, 0.f, 0.f, 0.f);
            if (gr < N_NODES)
                v = *(const float4*)&feat[(long)gr * IN_F + ks + lc + 4 * q];
            *(float4*)&As[lrow][lc + 4 * q] = v;
            *(float4*)&Bs[lrow][lc + 4 * q] =
                *(const float4*)&W[(ks + lrow) * OUT_F + lc + 4 * q];
        }
        __syncthreads();
        #pragma unroll
        for (int kq = 0; kq < 16; ++kq) {
            float4 a0 = *(const float4*)&As[ty +  0][4 * kq];
            float4 a1 = *(const float4*)&As[ty + 16][4 * kq];
            float4 a2 = *(const float4*)&As[ty + 32][4 * kq];
            float4 a3 = *(const float4*)&As[ty + 48][4 * kq];
            float4 b0 = *(const float4*)&Bs[4 * kq + 0][4 * tx];
            float4 b1 = *(const float4*)&Bs[4 * kq + 1][4 * tx];
            float4 b2 = *(const float4*)&Bs[4 * kq + 2][4 * tx];
            float4 b3 = *(const float4*)&Bs[4 * kq + 3][4 * tx];
#define FMA4(ACC, S, B) \
            ACC.x = fmaf(S, B.x, ACC.x); ACC.y = fmaf(S, B.y, ACC.y); \
            ACC.z = fmaf(S, B.z, ACC.z); ACC.w = fmaf(S, B.w, ACC.w);
            FMA4(acc[0], a0.x, b0) FMA4(acc[0], a0.y, b1) FMA4(acc[0], a0.z, b2) FMA4(acc[0], a0.w, b3)
            FMA4(acc[1], a1.x, b0) FMA4(acc[1], a1.y, b1) FMA4(acc[1], a1.z, b2) FMA4(acc[1], a1.w, b3)
            FMA4(acc[2], a2.x, b0) FMA4(acc[2], a2.y, b1) FMA4(acc[2], a2.z, b2) FMA4(acc[2], a2.w, b3)
            FMA4(acc[3], a3.x, b0) FMA4(acc[3], a3.y, b1) FMA4(acc[3], a3.z, b2) FMA4(acc[3], a3.w, b3)
#undef FMA4
        }
        __syncthreads();
    }
    #pragma unroll
    for (int i = 0; i < 4; ++i) {
        int r = row0 + ty + 16 * i;
        if (r < N_NODES) {
            float s = norm_out[r];
            float4 o = acc[i];
            o.x *= s; o.y *= s; o.z *= s; o.w *= s;
            *(float4*)&h[(long)r * OUT_F + 4 * tx] = o;
        }
    }
}

// --- aggregate: one wave per dst node; lane = feature. Fused norm+bias+relu. ---
__global__ __launch_bounds__(256) void agg_kernel(const int* __restrict__ row_ptr,
                                                  const unsigned* __restrict__ edge_src,
                                                  const float* __restrict__ h,
                                                  const float* __restrict__ bias,
                                                  float* __restrict__ out) {
    int wid  = (blockIdx.x * 256 + threadIdx.x) >> 6;
    int lane = threadIdx.x & 63;
    if (wid >= N_NODES) return;
    int start = row_ptr[wid];
    int end   = row_ptr[wid + 1];
    int deg   = end - start;

    float a0 = 0.f, a1 = 0.f, a2 = 0.f, a3 = 0.f;
    int e = start;
    for (; e + 4 <= end; e += 4) {
        int s0 = (int)edge_src[e + 0];
        int s1 = (int)edge_src[e + 1];
        int s2 = (int)edge_src[e + 2];
        int s3 = (int)edge_src[e + 3];
        a0 += h[(size_t)s0 * OUT_F + lane];
        a1 += h[(size_t)s1 * OUT_F + lane];
        a2 += h[(size_t)s2 * OUT_F + lane];
        a3 += h[(size_t)s3 * OUT_F + lane];
    }
    for (; e < end; ++e)
        a0 += h[(size_t)edge_src[e] * OUT_F + lane];

    int dc = deg < 1 ? 1 : deg;
    float r = (a0 + a1 + a2 + a3) * rsqrtf((float)dc) + bias[lane];
    out[(size_t)wid * OUT_F + lane] = fmaxf(r, 0.f);
}

extern "C" void kernel_launch(void* const* d_in, const int* in_sizes, int n_in,
                              void* d_out, int out_size, void* d_ws, size_t ws_size,
                              hipStream_t stream) {
    const float* feat = (const float*)d_in[0];
    const float* W    = (const float*)d_in[1];
    const float* bias = (const float*)d_in[2];
    const int*   src  = (const int*)d_in[3];
    const int*   dst  = (const int*)d_in[4];
    float* out = (float*)d_out;

    char* w = (char*)d_ws;
    size_t off = 0;
    auto take = [&](size_t bytes) { char* p = w + off; off += (bytes + 255) & ~(size_t)255; return p; };

    int*      hist_g   = (int*)take((size_t)MSIZE * 4);
    int*      partials = (int*)take((size_t)SC_BLOCKS * 4);
    int*      base_d   = (int*)take((size_t)(NB + 1) * 4);
    int*      base_s   = (int*)take((size_t)(NB + 1) * 4);
    float*    norm_out = (float*)take((size_t)NPAD * 4);
    int*      row_ptr  = (int*)take((size_t)(NPAD + 64) * 4);
    unsigned* edge_buf = (unsigned*)take((size_t)N_EDGES * 4);
    float*    h        = (float*)take((size_t)N_NODES * OUT_F * 4);
    int*      src_part = (int*)h;  // alias: consumed by normout before gemm writes h

    histA_kernel<<<NBLK, 256, 0, stream>>>(src, dst, hist_g);
    scan1_kernel<<<SC_BLOCKS, 256, 0, stream>>>(hist_g, partials);
    scan2_kernel<<<1, 1024, 0, stream>>>(partials);
    scan3_kernel<<<SC_BLOCKS, 256, 0, stream>>>(hist_g, partials, base_d, base_s);
    part_kernel<<<NBLK, 256, 0, stream>>>(src, dst, hist_g, edge_buf, src_part);
    normout_kernel<<<NB, 256, 0, stream>>>(src_part, base_s, norm_out);
    bucket_kernel<<<NB, 256, 0, stream>>>(edge_buf, base_d, row_ptr);
    gemm_kernel<<<(N_NODES + 63) / 64, 256, 0, stream>>>(feat, W, norm_out, h);
    agg_kernel<<<(N_NODES * 64 + 255) / 256, 256, 0, stream>>>(row_ptr, edge_buf, h, bias, out);
}

// Round 5
// 175.564 us; speedup vs baseline: 4.8342x; 1.1455x over previous
//
#include <hip/hip_runtime.h>

#define N_NODES 100000
#define N_EDGES 1600000
#define IN_F 256
#define OUT_F 64
#define NPAD 100096
#define NB 391            // node buckets of 256 nodes
#define NBLK 200          // partition blocks
#define CHUNK 8000        // edges per partition block (200*8000 = 1.6M exact)
#define MSIZE (2*NB*NBLK) // dst matrix then src matrix
#define SC_BLOCKS 612     // ceil(MSIZE/256)
#define CAP 12288         // LDS staging capacity per bucket

typedef __attribute__((ext_vector_type(8))) short short8v;
typedef __attribute__((ext_vector_type(4))) float f32x4;

// --- per-block bucket histograms (dst and src), no global atomics ---
__global__ __launch_bounds__(256) void histA_kernel(const int* __restrict__ src,
                                                    const int* __restrict__ dst,
                                                    int* __restrict__ hist_g) {
    __shared__ int hD[NB], hS[NB];
    int b = blockIdx.x, t = threadIdx.x;
    for (int j = t; j < NB; j += 256) { hD[j] = 0; hS[j] = 0; }
    __syncthreads();
    int e0 = b * CHUNK;
    for (int e = e0 + t; e < e0 + CHUNK; e += 256) {
        atomicAdd(&hD[dst[e] >> 8], 1);
        atomicAdd(&hS[src[e] >> 8], 1);
    }
    __syncthreads();
    for (int j = t; j < NB; j += 256) {
        hist_g[j * NBLK + b] = hD[j];
        hist_g[NB * NBLK + j * NBLK + b] = hS[j];
    }
}

// --- exclusive scan of hist_g[MSIZE] (in-place), 3 kernels ---
__global__ __launch_bounds__(256) void scan1_kernel(int* __restrict__ data,
                                                    int* __restrict__ partials) {
    __shared__ int sm[256];
    int i = blockIdx.x * 256 + threadIdx.x;
    int v = (i < MSIZE) ? data[i] : 0;
    sm[threadIdx.x] = v;
    __syncthreads();
    int x = v;
    #pragma unroll
    for (int off = 1; off < 256; off <<= 1) {
        int tv = 0;
        if ((int)threadIdx.x >= off) tv = sm[threadIdx.x - off];
        __syncthreads();
        x += tv;
        sm[threadIdx.x] = x;
        __syncthreads();
    }
    if (i < MSIZE) data[i] = x - v;
    if (threadIdx.x == 255) partials[blockIdx.x] = x;
}

__global__ __launch_bounds__(1024) void scan2_kernel(int* __restrict__ partials) {
    __shared__ int sm[1024];
    int i = threadIdx.x;
    int v = (i < SC_BLOCKS) ? partials[i] : 0;
    sm[i] = v;
    __syncthreads();
    int x = v;
    #pragma unroll
    for (int off = 1; off < 1024; off <<= 1) {
        int tv = 0;
        if (i >= off) tv = sm[i - off];
        __syncthreads();
        x += tv;
        sm[i] = x;
        __syncthreads();
    }
    if (i < SC_BLOCKS) partials[i] = x - v;
}

__global__ __launch_bounds__(256) void scan3_kernel(int* __restrict__ data,
                                                    const int* __restrict__ partials,
                                                    int* __restrict__ base_d,
                                                    int* __restrict__ base_s) {
    int i = blockIdx.x * 256 + threadIdx.x;
    if (i < MSIZE) {
        int v = data[i] + partials[blockIdx.x];
        data[i] = v;
        if (i % NBLK == 0) {
            int q = i / NBLK;
            if (q < NB) base_d[q] = v;
            else        base_s[q - NB] = v - N_EDGES;
        }
    }
    if (i == 0) { base_d[NB] = N_EDGES; base_s[NB] = N_EDGES; }
}

// --- partition edges into dst-buckets (packed dlocal|src) and src keys into src-buckets ---
__global__ __launch_bounds__(256) void part_kernel(const int* __restrict__ src,
                                                   const int* __restrict__ dst,
                                                   const int* __restrict__ hist_g,
                                                   unsigned* __restrict__ edge_buf,
                                                   int* __restrict__ src_part) {
    __shared__ int curD[NB], curS[NB];
    int b = blockIdx.x, t = threadIdx.x;
    for (int j = t; j < NB; j += 256) {
        curD[j] = hist_g[j * NBLK + b];
        curS[j] = hist_g[NB * NBLK + j * NBLK + b] - N_EDGES;
    }
    __syncthreads();
    int e0 = b * CHUNK;
    for (int e = e0 + t; e < e0 + CHUNK; e += 256) {
        int s = src[e], d = dst[e];
        int pD = atomicAdd(&curD[d >> 8], 1);
        edge_buf[pD] = ((unsigned)(d & 255) << 17) | (unsigned)s;
        int pS = atomicAdd(&curS[s >> 8], 1);
        src_part[pS] = s;
    }
}

// --- per-bucket out-degree -> norm_out ---
__global__ __launch_bounds__(256) void normout_kernel(const int* __restrict__ src_part,
                                                      const int* __restrict__ base_s,
                                                      float* __restrict__ norm_out) {
    __shared__ int hist[256];
    int j = blockIdx.x, t = threadIdx.x;
    hist[t] = 0;
    __syncthreads();
    int b0 = base_s[j], b1 = base_s[j + 1];
    for (int e = b0 + t; e < b1; e += 256)
        atomicAdd(&hist[src_part[e] & 255], 1);
    __syncthreads();
    int node = j * 256 + t;
    if (node < N_NODES) {
        int d = hist[t]; if (d < 1) d = 1;
        norm_out[node] = rsqrtf((float)d);
    }
}

// --- per-bucket in-LDS counting sort -> dst-sorted CSR (in place), emits row_ptr ---
__global__ __launch_bounds__(256) void bucket_kernel(unsigned* __restrict__ edge_buf,
                                                     const int* __restrict__ base_d,
                                                     int* __restrict__ row_ptr) {
    __shared__ unsigned stage[CAP];
    __shared__ int hist[256];
    __shared__ int cur[256];
    int j = blockIdx.x, t = threadIdx.x;
    int b0 = base_d[j], b1 = base_d[j + 1];
    int cnt = b1 - b0;
    hist[t] = 0;
    __syncthreads();
    for (int i = t; i < cnt; i += 256) {
        unsigned p = edge_buf[b0 + i];
        stage[i] = p;
        atomicAdd(&hist[p >> 17], 1);
    }
    __syncthreads();
    int v = hist[t];
    cur[t] = v;
    __syncthreads();
    int x = v;
    #pragma unroll
    for (int off = 1; off < 256; off <<= 1) {
        int tv = (t >= off) ? cur[t - off] : 0;
        __syncthreads();
        x += tv;
        cur[t] = x;
        __syncthreads();
    }
    int excl = x - v;
    row_ptr[j * 256 + t] = b0 + excl;
    cur[t] = excl;
    __syncthreads();
    for (int i = t; i < cnt; i += 256) {
        unsigned p = stage[i];
        int pos = atomicAdd(&cur[p >> 17], 1);
        edge_buf[b0 + pos] = p & 0x1FFFFu;
    }
}

// --- split a float into bf16 hi + bf16(residual) lo ---
__device__ __forceinline__ void split_bf16(float f, unsigned short& hi, unsigned short& lo) {
    unsigned u = __builtin_bit_cast(unsigned, f);
    unsigned r = (u + 0x7FFFu + ((u >> 16) & 1u)) >> 16;
    hi = (unsigned short)r;
    float hif = __builtin_bit_cast(float, r << 16);
    float l = f - hif;
    unsigned ul = __builtin_bit_cast(unsigned, l);
    unsigned rl = (ul + 0x7FFFu + ((ul >> 16) & 1u)) >> 16;
    lo = (unsigned short)rl;
}

// --- MFMA GEMM: h[r][c] = (sum_k feat[r][k]*W[k][c]) * norm_out[r]
//     bf16 3-term split (hi*hi + hi*lo + lo*hi) for ~fp32 accuracy.
//     128x64 block tile, BK=32, 4 waves; wave w: rows [32w,32w+32) x 64 cols.
#define BMT 128
#define BKT 32
#define KPT 40   // padded LDS pitch (shorts)
__global__ __launch_bounds__(256) void gemm_kernel(const float* __restrict__ feat,
                                                   const float* __restrict__ W,
                                                   const float* __restrict__ norm_out,
                                                   float* __restrict__ h) {
    __shared__ __attribute__((aligned(16))) unsigned short As_hi[BMT][KPT];
    __shared__ __attribute__((aligned(16))) unsigned short As_lo[BMT][KPT];
    __shared__ __attribute__((aligned(16))) unsigned short Bs_hi[OUT_F][KPT];
    __shared__ __attribute__((aligned(16))) unsigned short Bs_lo[OUT_F][KPT];
    const int tid  = threadIdx.x;
    const int wave = tid >> 6, lane = tid & 63;
    const int l15  = lane & 15, l4 = lane >> 4;
    const int row0 = blockIdx.x * BMT;

    // staging assignments
    const int arow  = tid >> 1;           // 0..127
    const int akoff = (tid & 1) * 16;     // 0 or 16
    const int bk    = tid >> 3;           // 0..31
    const int bcol0 = (tid & 7) * 8;      // 0..56

    f32x4 acc[2][4];
    #pragma unroll
    for (int rf = 0; rf < 2; ++rf)
        #pragma unroll
        for (int cf = 0; cf < 4; ++cf)
            acc[rf][cf] = (f32x4){0.f, 0.f, 0.f, 0.f};

    for (int ks = 0; ks < IN_F; ks += BKT) {
        // --- stage A tile (bf16 hi/lo) ---
        const int grow = row0 + arow;
        float v[16];
        if (grow < N_NODES) {
            const float* fp = &feat[(size_t)grow * IN_F + ks + akoff];
            #pragma unroll
            for (int q = 0; q < 4; ++q) {
                float4 tv = *(const float4*)(fp + 4 * q);
                v[4*q+0] = tv.x; v[4*q+1] = tv.y; v[4*q+2] = tv.z; v[4*q+3] = tv.w;
            }
        } else {
            #pragma unroll
            for (int q = 0; q < 16; ++q) v[q] = 0.f;
        }
        #pragma unroll
        for (int q = 0; q < 16; ++q) {
            unsigned short hi, lo;
            split_bf16(v[q], hi, lo);
            As_hi[arow][akoff + q] = hi;
            As_lo[arow][akoff + q] = lo;
        }
        // --- stage B tile transposed: Bs[col][k] ---
        {
            const float* wp = &W[(size_t)(ks + bk) * OUT_F + bcol0];
            #pragma unroll
            for (int q = 0; q < 8; ++q) {
                unsigned short hi, lo;
                split_bf16(wp[q], hi, lo);
                Bs_hi[bcol0 + q][bk] = hi;
                Bs_lo[bcol0 + q][bk] = lo;
            }
        }
        __syncthreads();

        // --- fragments + MFMA ---
        short8v a_hi[2], a_lo[2], b_hi[4], b_lo[4];
        #pragma unroll
        for (int rf = 0; rf < 2; ++rf) {
            int r = wave * 32 + rf * 16 + l15;
            a_hi[rf] = *(const short8v*)&As_hi[r][l4 * 8];
            a_lo[rf] = *(const short8v*)&As_lo[r][l4 * 8];
        }
        #pragma unroll
        for (int cf = 0; cf < 4; ++cf) {
            int c = cf * 16 + l15;
            b_hi[cf] = *(const short8v*)&Bs_hi[c][l4 * 8];
            b_lo[cf] = *(const short8v*)&Bs_lo[c][l4 * 8];
        }
        #pragma unroll
        for (int rf = 0; rf < 2; ++rf) {
            #pragma unroll
            for (int cf = 0; cf < 4; ++cf) {
                acc[rf][cf] = __builtin_amdgcn_mfma_f32_16x16x32_bf16(a_hi[rf], b_hi[cf], acc[rf][cf], 0, 0, 0);
                acc[rf][cf] = __builtin_amdgcn_mfma_f32_16x16x32_bf16(a_hi[rf], b_lo[cf], acc[rf][cf], 0, 0, 0);
                acc[rf][cf] = __builtin_amdgcn_mfma_f32_16x16x32_bf16(a_lo[rf], b_hi[cf], acc[rf][cf], 0, 0, 0);
            }
        }
        __syncthreads();
    }

    // --- epilogue: scale by norm_out, store h ---
    #pragma unroll
    for (int rf = 0; rf < 2; ++rf) {
        #pragma unroll
        for (int r = 0; r < 4; ++r) {
            int row = row0 + wave * 32 + rf * 16 + l4 * 4 + r;
            if (row < N_NODES) {
                float s = norm_out[row];
                #pragma unroll
                for (int cf = 0; cf < 4; ++cf)
                    h[(size_t)row * OUT_F + cf * 16 + l15] = acc[rf][cf][r] * s;
            }
        }
    }
}

// --- aggregate: one wave per dst node; lane = feature. Fused norm+bias+relu. ---
__global__ __launch_bounds__(256) void agg_kernel(const int* __restrict__ row_ptr,
                                                  const unsigned* __restrict__ edge_src,
                                                  const float* __restrict__ h,
                                                  const float* __restrict__ bias,
                                                  float* __restrict__ out) {
    int wid  = (blockIdx.x * 256 + threadIdx.x) >> 6;
    int lane = threadIdx.x & 63;
    if (wid >= N_NODES) return;
    int start = row_ptr[wid];
    int end   = row_ptr[wid + 1];
    int deg   = end - start;

    float a0 = 0.f, a1 = 0.f, a2 = 0.f, a3 = 0.f;
    int e = start;
    for (; e + 4 <= end; e += 4) {
        int s0 = (int)edge_src[e + 0];
        int s1 = (int)edge_src[e + 1];
        int s2 = (int)edge_src[e + 2];
        int s3 = (int)edge_src[e + 3];
        a0 += h[(size_t)s0 * OUT_F + lane];
        a1 += h[(size_t)s1 * OUT_F + lane];
        a2 += h[(size_t)s2 * OUT_F + lane];
        a3 += h[(size_t)s3 * OUT_F + lane];
    }
    for (; e < end; ++e)
        a0 += h[(size_t)edge_src[e] * OUT_F + lane];

    int dc = deg < 1 ? 1 : deg;
    float r = (a0 + a1 + a2 + a3) * rsqrtf((float)dc) + bias[lane];
    out[(size_t)wid * OUT_F + lane] = fmaxf(r, 0.f);
}

extern "C" void kernel_launch(void* const* d_in, const int* in_sizes, int n_in,
                              void* d_out, int out_size, void* d_ws, size_t ws_size,
                              hipStream_t stream) {
    const float* feat = (const float*)d_in[0];
    const float* W    = (const float*)d_in[1];
    const float* bias = (const float*)d_in[2];
    const int*   src  = (const int*)d_in[3];
    const int*   dst  = (const int*)d_in[4];
    float* out = (float*)d_out;

    char* w = (char*)d_ws;
    size_t off = 0;
    auto take = [&](size_t bytes) { char* p = w + off; off += (bytes + 255) & ~(size_t)255; return p; };

    int*      hist_g   = (int*)take((size_t)MSIZE * 4);
    int*      partials = (int*)take((size_t)SC_BLOCKS * 4);
    int*      base_d   = (int*)take((size_t)(NB + 1) * 4);
    int*      base_s   = (int*)take((size_t)(NB + 1) * 4);
    float*    norm_out = (float*)take((size_t)NPAD * 4);
    int*      row_ptr  = (int*)take((size_t)(NPAD + 64) * 4);
    unsigned* edge_buf = (unsigned*)take((size_t)N_EDGES * 4);
    float*    h        = (float*)take((size_t)N_NODES * OUT_F * 4);
    int*      src_part = (int*)h;  // alias: consumed by normout before gemm writes h

    histA_kernel<<<NBLK, 256, 0, stream>>>(src, dst, hist_g);
    scan1_kernel<<<SC_BLOCKS, 256, 0, stream>>>(hist_g, partials);
    scan2_kernel<<<1, 1024, 0, stream>>>(partials);
    scan3_kernel<<<SC_BLOCKS, 256, 0, stream>>>(hist_g, partials, base_d, base_s);
    part_kernel<<<NBLK, 256, 0, stream>>>(src, dst, hist_g, edge_buf, src_part);
    normout_kernel<<<NB, 256, 0, stream>>>(src_part, base_s, norm_out);
    bucket_kernel<<<NB, 256, 0, stream>>>(edge_buf, base_d, row_ptr);
    gemm_kernel<<<(NPAD / BMT), 256, 0, stream>>>(feat, W, norm_out, h);
    agg_kernel<<<(N_NODES * 64 + 255) / 256, 256, 0, stream>>>(row_ptr, edge_buf, h, bias, out);
}

// Round 6
// 159.992 us; speedup vs baseline: 5.3047x; 1.0973x over previous
//
#include <hip/hip_runtime.h>

#define N_NODES 100000
#define N_EDGES 1600000
#define IN_F 256
#define OUT_F 64
#define NPAD 100096
#define NB 391            // node buckets of 256 nodes
#define NBLK 200          // partition blocks
#define CHUNK 8000        // edges per partition block (200*8000 = 1.6M exact)
#define MSIZE (2*NB*NBLK) // dst matrix then src matrix
#define SC_BLOCKS 612     // ceil(MSIZE/256)
#define CAP 12288         // LDS staging capacity per bucket

typedef __attribute__((ext_vector_type(8))) short short8v;
typedef __attribute__((ext_vector_type(4))) float f32x4;

__device__ __forceinline__ unsigned short f2bf(float f) {
    unsigned u = __builtin_bit_cast(unsigned, f);
    return (unsigned short)((u + 0x7FFFu + ((u >> 16) & 1u)) >> 16);
}
__device__ __forceinline__ float bf2f(unsigned s) {
    return __builtin_bit_cast(float, s << 16);
}

// --- per-block bucket histograms (dst and src), no global atomics ---
__global__ __launch_bounds__(256) void histA_kernel(const int* __restrict__ src,
                                                    const int* __restrict__ dst,
                                                    int* __restrict__ hist_g) {
    __shared__ int hD[NB], hS[NB];
    int b = blockIdx.x, t = threadIdx.x;
    for (int j = t; j < NB; j += 256) { hD[j] = 0; hS[j] = 0; }
    __syncthreads();
    int e0 = b * CHUNK;
    for (int e = e0 + t; e < e0 + CHUNK; e += 256) {
        atomicAdd(&hD[dst[e] >> 8], 1);
        atomicAdd(&hS[src[e] >> 8], 1);
    }
    __syncthreads();
    for (int j = t; j < NB; j += 256) {
        hist_g[j * NBLK + b] = hD[j];
        hist_g[NB * NBLK + j * NBLK + b] = hS[j];
    }
}

// --- exclusive scan of hist_g[MSIZE] (in-place), 3 kernels ---
__global__ __launch_bounds__(256) void scan1_kernel(int* __restrict__ data,
                                                    int* __restrict__ partials) {
    __shared__ int sm[256];
    int i = blockIdx.x * 256 + threadIdx.x;
    int v = (i < MSIZE) ? data[i] : 0;
    sm[threadIdx.x] = v;
    __syncthreads();
    int x = v;
    #pragma unroll
    for (int off = 1; off < 256; off <<= 1) {
        int tv = 0;
        if ((int)threadIdx.x >= off) tv = sm[threadIdx.x - off];
        __syncthreads();
        x += tv;
        sm[threadIdx.x] = x;
        __syncthreads();
    }
    if (i < MSIZE) data[i] = x - v;
    if (threadIdx.x == 255) partials[blockIdx.x] = x;
}

__global__ __launch_bounds__(1024) void scan2_kernel(int* __restrict__ partials) {
    __shared__ int sm[1024];
    int i = threadIdx.x;
    int v = (i < SC_BLOCKS) ? partials[i] : 0;
    sm[i] = v;
    __syncthreads();
    int x = v;
    #pragma unroll
    for (int off = 1; off < 1024; off <<= 1) {
        int tv = 0;
        if (i >= off) tv = sm[i - off];
        __syncthreads();
        x += tv;
        sm[i] = x;
        __syncthreads();
    }
    if (i < SC_BLOCKS) partials[i] = x - v;
}

__global__ __launch_bounds__(256) void scan3_kernel(int* __restrict__ data,
                                                    const int* __restrict__ partials,
                                                    int* __restrict__ base_d,
                                                    int* __restrict__ base_s) {
    int i = blockIdx.x * 256 + threadIdx.x;
    if (i < MSIZE) {
        int v = data[i] + partials[blockIdx.x];
        data[i] = v;
        if (i % NBLK == 0) {
            int q = i / NBLK;
            if (q < NB) base_d[q] = v;
            else        base_s[q - NB] = v - N_EDGES;
        }
    }
    if (i == 0) { base_d[NB] = N_EDGES; base_s[NB] = N_EDGES; }
}

// --- partition edges into dst-buckets (packed dlocal|src) and src keys into src-buckets ---
__global__ __launch_bounds__(256) void part_kernel(const int* __restrict__ src,
                                                   const int* __restrict__ dst,
                                                   const int* __restrict__ hist_g,
                                                   unsigned* __restrict__ edge_buf,
                                                   int* __restrict__ src_part) {
    __shared__ int curD[NB], curS[NB];
    int b = blockIdx.x, t = threadIdx.x;
    for (int j = t; j < NB; j += 256) {
        curD[j] = hist_g[j * NBLK + b];
        curS[j] = hist_g[NB * NBLK + j * NBLK + b] - N_EDGES;
    }
    __syncthreads();
    int e0 = b * CHUNK;
    for (int e = e0 + t; e < e0 + CHUNK; e += 256) {
        int s = src[e], d = dst[e];
        int pD = atomicAdd(&curD[d >> 8], 1);
        edge_buf[pD] = ((unsigned)(d & 255) << 17) | (unsigned)s;
        int pS = atomicAdd(&curS[s >> 8], 1);
        src_part[pS] = s;
    }
}

// --- per-bucket out-degree -> norm_out ---
__global__ __launch_bounds__(256) void normout_kernel(const int* __restrict__ src_part,
                                                      const int* __restrict__ base_s,
                                                      float* __restrict__ norm_out) {
    __shared__ int hist[256];
    int j = blockIdx.x, t = threadIdx.x;
    hist[t] = 0;
    __syncthreads();
    int b0 = base_s[j], b1 = base_s[j + 1];
    for (int e = b0 + t; e < b1; e += 256)
        atomicAdd(&hist[src_part[e] & 255], 1);
    __syncthreads();
    int node = j * 256 + t;
    if (node < N_NODES) {
        int d = hist[t]; if (d < 1) d = 1;
        norm_out[node] = rsqrtf((float)d);
    }
}

// --- per-bucket in-LDS counting sort -> dst-sorted CSR (in place), emits row_ptr ---
__global__ __launch_bounds__(256) void bucket_kernel(unsigned* __restrict__ edge_buf,
                                                     const int* __restrict__ base_d,
                                                     int* __restrict__ row_ptr) {
    __shared__ unsigned stage[CAP];
    __shared__ int hist[256];
    __shared__ int cur[256];
    int j = blockIdx.x, t = threadIdx.x;
    int b0 = base_d[j], b1 = base_d[j + 1];
    int cnt = b1 - b0;
    hist[t] = 0;
    __syncthreads();
    for (int i = t; i < cnt; i += 256) {
        unsigned p = edge_buf[b0 + i];
        stage[i] = p;
        atomicAdd(&hist[p >> 17], 1);
    }
    __syncthreads();
    int v = hist[t];
    cur[t] = v;
    __syncthreads();
    int x = v;
    #pragma unroll
    for (int off = 1; off < 256; off <<= 1) {
        int tv = (t >= off) ? cur[t - off] : 0;
        __syncthreads();
        x += tv;
        cur[t] = x;
        __syncthreads();
    }
    int excl = x - v;
    row_ptr[j * 256 + t] = b0 + excl;
    cur[t] = excl;
    __syncthreads();
    for (int i = t; i < cnt; i += 256) {
        unsigned p = stage[i];
        int pos = atomicAdd(&cur[p >> 17], 1);
        edge_buf[b0 + pos] = p & 0x1FFFFu;
    }
}

// --- split a float into bf16 hi + bf16(residual) lo ---
__device__ __forceinline__ void split_bf16(float f, unsigned short& hi, unsigned short& lo) {
    unsigned u = __builtin_bit_cast(unsigned, f);
    unsigned r = (u + 0x7FFFu + ((u >> 16) & 1u)) >> 16;
    hi = (unsigned short)r;
    float hif = __builtin_bit_cast(float, r << 16);
    float l = f - hif;
    unsigned ul = __builtin_bit_cast(unsigned, l);
    unsigned rl = (ul + 0x7FFFu + ((ul >> 16) & 1u)) >> 16;
    lo = (unsigned short)rl;
}

// --- MFMA GEMM: h[r][c] = (sum_k feat[r][k]*W[k][c]) * norm_out[r], h stored bf16.
#define BMT 128
#define BKT 32
#define KPT 40   // padded LDS pitch (shorts)
__global__ __launch_bounds__(256) void gemm_kernel(const float* __restrict__ feat,
                                                   const float* __restrict__ W,
                                                   const float* __restrict__ norm_out,
                                                   unsigned short* __restrict__ h) {
    __shared__ __attribute__((aligned(16))) unsigned short As_hi[BMT][KPT];
    __shared__ __attribute__((aligned(16))) unsigned short As_lo[BMT][KPT];
    __shared__ __attribute__((aligned(16))) unsigned short Bs_hi[OUT_F][KPT];
    __shared__ __attribute__((aligned(16))) unsigned short Bs_lo[OUT_F][KPT];
    const int tid  = threadIdx.x;
    const int wave = tid >> 6, lane = tid & 63;
    const int l15  = lane & 15, l4 = lane >> 4;
    const int row0 = blockIdx.x * BMT;

    const int arow  = tid >> 1;
    const int akoff = (tid & 1) * 16;
    const int bk    = tid >> 3;
    const int bcol0 = (tid & 7) * 8;

    f32x4 acc[2][4];
    #pragma unroll
    for (int rf = 0; rf < 2; ++rf)
        #pragma unroll
        for (int cf = 0; cf < 4; ++cf)
            acc[rf][cf] = (f32x4){0.f, 0.f, 0.f, 0.f};

    for (int ks = 0; ks < IN_F; ks += BKT) {
        const int grow = row0 + arow;
        float v[16];
        if (grow < N_NODES) {
            const float* fp = &feat[(size_t)grow * IN_F + ks + akoff];
            #pragma unroll
            for (int q = 0; q < 4; ++q) {
                float4 tv = *(const float4*)(fp + 4 * q);
                v[4*q+0] = tv.x; v[4*q+1] = tv.y; v[4*q+2] = tv.z; v[4*q+3] = tv.w;
            }
        } else {
            #pragma unroll
            for (int q = 0; q < 16; ++q) v[q] = 0.f;
        }
        #pragma unroll
        for (int q = 0; q < 16; ++q) {
            unsigned short hi, lo;
            split_bf16(v[q], hi, lo);
            As_hi[arow][akoff + q] = hi;
            As_lo[arow][akoff + q] = lo;
        }
        {
            const float* wp = &W[(size_t)(ks + bk) * OUT_F + bcol0];
            #pragma unroll
            for (int q = 0; q < 8; ++q) {
                unsigned short hi, lo;
                split_bf16(wp[q], hi, lo);
                Bs_hi[bcol0 + q][bk] = hi;
                Bs_lo[bcol0 + q][bk] = lo;
            }
        }
        __syncthreads();

        short8v a_hi[2], a_lo[2], b_hi[4], b_lo[4];
        #pragma unroll
        for (int rf = 0; rf < 2; ++rf) {
            int r = wave * 32 + rf * 16 + l15;
            a_hi[rf] = *(const short8v*)&As_hi[r][l4 * 8];
            a_lo[rf] = *(const short8v*)&As_lo[r][l4 * 8];
        }
        #pragma unroll
        for (int cf = 0; cf < 4; ++cf) {
            int c = cf * 16 + l15;
            b_hi[cf] = *(const short8v*)&Bs_hi[c][l4 * 8];
            b_lo[cf] = *(const short8v*)&Bs_lo[c][l4 * 8];
        }
        #pragma unroll
        for (int rf = 0; rf < 2; ++rf) {
            #pragma unroll
            for (int cf = 0; cf < 4; ++cf) {
                acc[rf][cf] = __builtin_amdgcn_mfma_f32_16x16x32_bf16(a_hi[rf], b_hi[cf], acc[rf][cf], 0, 0, 0);
                acc[rf][cf] = __builtin_amdgcn_mfma_f32_16x16x32_bf16(a_hi[rf], b_lo[cf], acc[rf][cf], 0, 0, 0);
                acc[rf][cf] = __builtin_amdgcn_mfma_f32_16x16x32_bf16(a_lo[rf], b_hi[cf], acc[rf][cf], 0, 0, 0);
            }
        }
        __syncthreads();
    }

    // epilogue: scale by norm_out, store h as bf16
    #pragma unroll
    for (int rf = 0; rf < 2; ++rf) {
        #pragma unroll
        for (int r = 0; r < 4; ++r) {
            int row = row0 + wave * 32 + rf * 16 + l4 * 4 + r;
            if (row < N_NODES) {
                float s = norm_out[row];
                #pragma unroll
                for (int cf = 0; cf < 4; ++cf)
                    h[(size_t)row * OUT_F + cf * 16 + l15] = f2bf(acc[rf][cf][r] * s);
            }
        }
    }
}

// --- aggregate: one wave per dst node. Lanes 0-31 <-> edge e, 32-63 <-> edge e+1;
//     each lane loads bf16x2 (features 2*sl, 2*sl+1). Fused norm+bias+relu. ---
__global__ __launch_bounds__(256) void agg_kernel(const int* __restrict__ row_ptr,
                                                  const unsigned* __restrict__ edge_src,
                                                  const unsigned short* __restrict__ h,
                                                  const float* __restrict__ bias,
                                                  float* __restrict__ out) {
    int wid  = (blockIdx.x * 256 + threadIdx.x) >> 6;
    int lane = threadIdx.x & 63;
    if (wid >= N_NODES) return;
    int half = lane >> 5;           // 0 or 1
    int sl   = lane & 31;           // feature pair index
    int start = row_ptr[wid];
    int end   = row_ptr[wid + 1];
    int deg   = end - start;

    float ax0 = 0.f, ay0 = 0.f, ax1 = 0.f, ay1 = 0.f;
    int e = start + half;
    // main loop: 8 edges per iteration (4 per half)
    for (; e + 7 < end + half; e += 8) {
        #pragma unroll
        for (int k = 0; k < 4; ++k) {
            int s = (int)edge_src[e + 2 * k];
            unsigned wv = *(const unsigned*)&h[(size_t)s * OUT_F + sl * 2];
            if (k & 1) { ax1 += bf2f(wv & 0xFFFFu); ay1 += bf2f(wv >> 16); }
            else       { ax0 += bf2f(wv & 0xFFFFu); ay0 += bf2f(wv >> 16); }
        }
    }
    for (; e < end; e += 2) {
        int s = (int)edge_src[e];
        unsigned wv = *(const unsigned*)&h[(size_t)s * OUT_F + sl * 2];
        ax0 += bf2f(wv & 0xFFFFu); ay0 += bf2f(wv >> 16);
    }
    float ax = ax0 + ax1, ay = ay0 + ay1;
    // combine halves: lane l += lane l^32
    ax += __shfl_xor(ax, 32);
    ay += __shfl_xor(ay, 32);

    if (half == 0) {
        int dc = deg < 1 ? 1 : deg;
        float nrm = rsqrtf((float)dc);
        float2 r;
        r.x = fmaxf(ax * nrm + bias[sl * 2 + 0], 0.f);
        r.y = fmaxf(ay * nrm + bias[sl * 2 + 1], 0.f);
        *(float2*)&out[(size_t)wid * OUT_F + sl * 2] = r;
    }
}

extern "C" void kernel_launch(void* const* d_in, const int* in_sizes, int n_in,
                              void* d_out, int out_size, void* d_ws, size_t ws_size,
                              hipStream_t stream) {
    const float* feat = (const float*)d_in[0];
    const float* W    = (const float*)d_in[1];
    const float* bias = (const float*)d_in[2];
    const int*   src  = (const int*)d_in[3];
    const int*   dst  = (const int*)d_in[4];
    float* out = (float*)d_out;

    char* w = (char*)d_ws;
    size_t off = 0;
    auto take = [&](size_t bytes) { char* p = w + off; off += (bytes + 255) & ~(size_t)255; return p; };

    int*            hist_g   = (int*)take((size_t)MSIZE * 4);
    int*            partials = (int*)take((size_t)SC_BLOCKS * 4);
    int*            base_d   = (int*)take((size_t)(NB + 1) * 4);
    int*            base_s   = (int*)take((size_t)(NB + 1) * 4);
    float*          norm_out = (float*)take((size_t)NPAD * 4);
    int*            row_ptr  = (int*)take((size_t)(NPAD + 64) * 4);
    unsigned*       edge_buf = (unsigned*)take((size_t)N_EDGES * 4);
    unsigned short* h        = (unsigned short*)take((size_t)N_NODES * OUT_F * 4); // slack ok
    int*            src_part = (int*)h;  // alias: consumed by normout before gemm writes h

    histA_kernel<<<NBLK, 256, 0, stream>>>(src, dst, hist_g);
    scan1_kernel<<<SC_BLOCKS, 256, 0, stream>>>(hist_g, partials);
    scan2_kernel<<<1, 1024, 0, stream>>>(partials);
    scan3_kernel<<<SC_BLOCKS, 256, 0, stream>>>(hist_g, partials, base_d, base_s);
    part_kernel<<<NBLK, 256, 0, stream>>>(src, dst, hist_g, edge_buf, src_part);
    normout_kernel<<<NB, 256, 0, stream>>>(src_part, base_s, norm_out);
    bucket_kernel<<<NB, 256, 0, stream>>>(edge_buf, base_d, row_ptr);
    gemm_kernel<<<(NPAD / BMT), 256, 0, stream>>>(feat, W, norm_out, h);
    agg_kernel<<<(N_NODES * 64 + 255) / 256, 256, 0, stream>>>(row_ptr, edge_buf, h, bias, out);
}